// Round 2
// 1768.041 us; speedup vs baseline: 1.0557x; 1.0557x over previous
//
#include <hip/hip_runtime.h>
#include <hip/hip_bf16.h>

#define N_NODES 50000
#define N_PAD   50016          // padded to 32-row blocks for k_fp_mfma
#define NODE_F  192
#define EDGE_F  64
#define DIM     256
#define OUT_DIM 2048
#define DEPTH   3
#define M_EDGES 800000

typedef short  bf16x8 __attribute__((ext_vector_type(8)));   // 8 bf16 in 4 VGPRs
typedef float  f32x4  __attribute__((ext_vector_type(4)));

__device__ inline short f2bf(float f) {
    unsigned u = __float_as_uint(f);
    unsigned r = (u + 0x7fffu + ((u >> 16) & 1u)) >> 16;
    return (short)r;
}

// async global->LDS, 16B per lane; LDS dest is wave-uniform base + lane*16
#define GLDS16(g, l) __builtin_amdgcn_global_load_lds(                        \
    (const __attribute__((address_space(1))) void*)(g),                       \
    (__attribute__((address_space(3))) void*)(l), 16, 0, 0)

#define MEMFENCE() asm volatile("" ::: "memory")

// ---------------------------------------------------------------------------
// attr = [node_attr | zeros(EDGE_F)] -> [N,256] fp32, plus bf16 mirror
// ---------------------------------------------------------------------------
__global__ void k_init_attr(const float* __restrict__ node_attr,
                            float* __restrict__ attr,
                            short* __restrict__ attr_bf) {
    int i = blockIdx.x * 256 + threadIdx.x;   // float4/short4 slot over N_PAD*64
    int row = i >> 6, q = i & 63;
    if (row >= N_PAD) return;
    float4 v = make_float4(0.f, 0.f, 0.f, 0.f);
    if (row < N_NODES && q < NODE_F / 4)
        v = ((const float4*)node_attr)[row * (NODE_F / 4) + q];
    if (row < N_NODES) ((float4*)attr)[i] = v;
    short4 s; s.x = f2bf(v.x); s.y = f2bf(v.y); s.z = f2bf(v.z); s.w = f2bf(v.w);
    ((short4*)attr_bf)[i] = s;
}

// ---------------------------------------------------------------------------
// CSR build: degree histogram -> single-block scan -> edge-index fill
// ---------------------------------------------------------------------------
__global__ void k_degree(const int* __restrict__ dst, int* __restrict__ deg) {
    int e = blockIdx.x * 256 + threadIdx.x;
    if (e < M_EDGES) atomicAdd(&deg[dst[e]], 1);
}

__global__ __launch_bounds__(1024) void k_scan(int* __restrict__ deg,
                                               int* __restrict__ rowptr) {
    __shared__ int part[1024];
    int t = threadIdx.x;
    const int CH = (N_NODES + 1023) / 1024;   // 49
    int beg = t * CH, end = min(beg + CH, N_NODES);
    int s = 0;
    for (int i = beg; i < end; i++) s += deg[i];
    part[t] = s;
    __syncthreads();
    for (int off = 1; off < 1024; off <<= 1) {
        int v = (t >= off) ? part[t - off] : 0;
        __syncthreads();
        part[t] += v;
        __syncthreads();
    }
    int run = (t == 0) ? 0 : part[t - 1];
    for (int i = beg; i < end; i++) {
        int d = deg[i];
        rowptr[i] = run;
        deg[i] = run;      // cursor for k_fill
        run += d;
    }
    if (t == 1023) rowptr[N_NODES] = run;
}

// fill: eidx (edge id, dst-sorted) and srcs (source node, dst-sorted)
__global__ void k_fill(const int* __restrict__ dst, const int* __restrict__ src,
                       int* __restrict__ cursor,
                       int* __restrict__ eidx, int* __restrict__ srcs) {
    int e = blockIdx.x * 256 + threadIdx.x;
    if (e < M_EDGES) {
        int p = atomicAdd(&cursor[dst[e]], 1);
        eidx[p] = e;
        srcs[p] = src[e];
    }
}

// ---------------------------------------------------------------------------
// esum[i] = sum_{e : dst[e]==i} edge_attr[e]   (depth-invariant, [N,64] f32)
// 16 threads per node, one float4 lane each.
// ---------------------------------------------------------------------------
__global__ __launch_bounds__(256) void k_esum(const float* __restrict__ edge_attr,
                                              const int* __restrict__ rowptr,
                                              const int* __restrict__ eidx,
                                              float* __restrict__ esum) {
    int gid = blockIdx.x * 256 + threadIdx.x;   // over N*16
    int node = gid >> 4, q = gid & 15;
    if (node >= N_NODES) return;
    int beg = rowptr[node], end = rowptr[node + 1];
    float4 acc = make_float4(0.f, 0.f, 0.f, 0.f);
    const float4* E4 = (const float4*)edge_attr;
    for (int i = beg; i < end; i++) {
        int e = eidx[i];
        float4 v = E4[(size_t)e * 16 + q];
        acc.x += v.x; acc.y += v.y; acc.z += v.z; acc.w += v.w;
    }
    ((float4*)esum)[(size_t)node * 16 + q] = acc;
}

// ---------------------------------------------------------------------------
// gather: agg[i] = esum_pad[i] + sum_{e : dst[e]==i} attr[srcs]
// one wave (64 lanes x float4) per node; srcs is dst-sorted (sequential).
// ---------------------------------------------------------------------------
__global__ __launch_bounds__(256) void k_gather(const float* __restrict__ attr,
                                                const int* __restrict__ rowptr,
                                                const int* __restrict__ srcs,
                                                const float* __restrict__ esum,
                                                float* __restrict__ agg) {
    int gid = blockIdx.x * 256 + threadIdx.x;
    int node = gid >> 6, q = gid & 63;
    if (node >= N_NODES) return;
    int beg = rowptr[node], end = rowptr[node + 1];
    float4 acc = make_float4(0.f, 0.f, 0.f, 0.f);
    if (q >= NODE_F / 4)
        acc = ((const float4*)esum)[(size_t)node * 16 + (q - NODE_F / 4)];
    const float4* A4 = (const float4*)attr;
    for (int i = beg; i < end; i++) {
        int s = srcs[i];                 // wave-uniform sequential load
        float4 v = A4[(size_t)s * 64 + q];
        acc.x += v.x; acc.y += v.y; acc.z += v.z; acc.w += v.w;
    }
    ((float4*)agg)[(size_t)node * 64 + q] = acc;
}

// ---------------------------------------------------------------------------
// inner GEMM: attr_new = (attr + agg) @ W + b, in-place on attr (fp32 vector),
// also writes the bf16 mirror used by k_fp_mfma.
// ---------------------------------------------------------------------------
__global__ __launch_bounds__(256) void k_inner(const float* __restrict__ attr,
                                               const float* __restrict__ agg,
                                               const float* __restrict__ W,
                                               const float* __restrict__ b,
                                               float* __restrict__ out,
                                               short* __restrict__ out_bf) {
    __shared__ float4 sV[32][64];   // 32 KB
    int tid  = threadIdx.x;
    int row0 = blockIdx.x * 32;

    for (int i = tid; i < 32 * 64; i += 256) {
        int r = i >> 6, q = i & 63;
        int grow = row0 + r;
        float4 v = make_float4(0.f, 0.f, 0.f, 0.f);
        if (grow < N_NODES) {
            float4 a = ((const float4*)attr)[(size_t)grow * 64 + q];
            float4 g = ((const float4*)agg)[(size_t)grow * 64 + q];
            v = make_float4(a.x + g.x, a.y + g.y, a.z + g.z, a.w + g.w);
        }
        sV[r][q] = v;
    }
    __syncthreads();

    int cg = tid & 63;
    int rg = tid >> 6;

    float4 acc[8];
#pragma unroll
    for (int r = 0; r < 8; r++) acc[r] = make_float4(0.f, 0.f, 0.f, 0.f);

    const float4* W4 = (const float4*)W;
    for (int k4 = 0; k4 < 64; k4++) {
        float4 w0 = W4[(size_t)(k4 * 4 + 0) * 64 + cg];
        float4 w1 = W4[(size_t)(k4 * 4 + 1) * 64 + cg];
        float4 w2 = W4[(size_t)(k4 * 4 + 2) * 64 + cg];
        float4 w3 = W4[(size_t)(k4 * 4 + 3) * 64 + cg];
#pragma unroll
        for (int r = 0; r < 8; r++) {
            float4 a = sV[rg * 8 + r][k4];
            acc[r].x += a.x * w0.x + a.y * w1.x + a.z * w2.x + a.w * w3.x;
            acc[r].y += a.x * w0.y + a.y * w1.y + a.z * w2.y + a.w * w3.y;
            acc[r].z += a.x * w0.z + a.y * w1.z + a.z * w2.z + a.w * w3.z;
            acc[r].w += a.x * w0.w + a.y * w1.w + a.z * w2.w + a.w * w3.w;
        }
    }

    float4 bb = ((const float4*)b)[cg];
#pragma unroll
    for (int r = 0; r < 8; r++) {
        int grow = row0 + rg * 8 + r;
        if (grow < N_NODES) {
            float4 o = make_float4(acc[r].x + bb.x, acc[r].y + bb.y,
                                   acc[r].z + bb.z, acc[r].w + bb.w);
            ((float4*)out)[(size_t)grow * 64 + cg] = o;
            short4 s; s.x = f2bf(o.x); s.y = f2bf(o.y); s.z = f2bf(o.z); s.w = f2bf(o.w);
            ((short4*)out_bf)[(size_t)grow * 64 + cg] = s;
        }
    }
}

// ---------------------------------------------------------------------------
// W_output swizzle: fp32 [4][256][2048] -> bf16 fragment layout, UNIT-MAJOR:
// unit uu = ks*2 + h (h = t>>2) is a contiguous 64 KB block of fragments
// ordered [w][j=t&3][lane], so k_fp_mfma can stage one unit with linear
// global_load_lds.
// ---------------------------------------------------------------------------
__global__ void k_wswz(const float* __restrict__ W, short* __restrict__ Wz) {
    int idx = blockIdx.x * 256 + threadIdx.x;    // 2^18 total
    int lane = idx & 63;
    int T    = (idx >> 6) & 127;
    int ks   = (idx >> 13) & 7;
    int d    = idx >> 16;
    int quad = lane >> 4;
    int m    = lane & 15;
    const float* src = W + ((size_t)(d * 256 + ks * 32 + quad * 8)) * 2048 + T * 16 + m;
    int w = T >> 3, h = (T >> 2) & 1, j = T & 3;
    size_t n = ((((size_t)(ks * 2 + h)) * 16 + w) * 4 + j) * 64 + lane;
    short* dstp = Wz + ((size_t)d * 65536 + n) * 8;
#pragma unroll
    for (int jj = 0; jj < 8; jj++) dstp[jj] = f2bf(src[(size_t)jj * 2048]);
}

// ---------------------------------------------------------------------------
// fp contribution via MFMA: fp_part += colsum(softmax(attr @ W + b))
// 32 rows/block, 1024 thr = 16 waves; wave = 32 rows x 128 cols.
// C/D layout: col = lane&15, row = (lane>>4)*4 + reg.
//
// Schedule (T2+T3+T4+T5):
//  - A tile (32x256 bf16) staged once into LDS via global_load_lds with
//    XOR-swizzled SOURCE (byte ^= (row&7)<<4); reads apply the same XOR.
//  - B staged in 16 "units" (ks,half) of 64 KB each, double-buffered in LDS
//    via global_load_lds (zero VGPR cost), counted s_waitcnt vmcnt(4) +
//    raw s_barrier (NOT __syncthreads: that drains vmcnt(0)).
//  - u=0 drains vmcnt(0) once: GLDS issue order within the prologue is not
//    guaranteed, so a counted wait there would be unsound. Steady-state
//    keeps the counted vmcnt(4); every stage_unit is bracketed by
//    asm-volatile memory fences so loads cannot migrate across iterations.
// ---------------------------------------------------------------------------
__global__ __launch_bounds__(1024)
void k_fp_mfma(const short* __restrict__ attr_bf,
               const short* __restrict__ Wz,    // depth offset applied by host
               const float* __restrict__ bias,
               float* __restrict__ fp_part) {
    __shared__ __align__(16) short A_lds[32 * 256];      // 16 KB (swizzled)
    __shared__ __align__(16) short B_lds[2][4096 * 8];   // 2 x 64 KB units
    __shared__ float sred[32][17];
    __shared__ float sfinm[32];
    __shared__ float sfinl[32];
    int tid  = threadIdx.x;
    int lane = tid & 63;
    int wave = tid >> 6;          // 0..15
    int quad = lane >> 4;
    int m    = lane & 15;
    int row0 = blockIdx.x * 32;
    int sw   = (m & 7) << 4;      // A-tile XOR swizzle term

    // ---- prologue: stage A tile (swizzled source) + units 0,1 ----
    {
        int r   = tid >> 5;               // row 0..31
        int c16 = tid & 31;               // 16B slot in row
        const char* gsrc = (const char*)attr_bf
            + (size_t)(row0 + r) * 512 + (size_t)((c16 * 16) ^ ((r & 7) << 4));
        char* ldst = (char*)A_lds + (size_t)wave * 1024;   // + lane*16 by HW
        GLDS16(gsrc, ldst);
    }
    MEMFENCE();
    auto stage_unit = [&](int uu, int b) {
        const char* gb = (const char*)Wz + (size_t)uu * 65536 + (size_t)tid * 16;
        char* lb = (char*)(&B_lds[b][0]) + wave * 1024;    // + lane*16 by HW
#pragma unroll
        for (int p = 0; p < 4; p++)
            GLDS16(gb + p * 16384, lb + p * 16384);
    };
    stage_unit(0, 0);
    MEMFENCE();
    stage_unit(1, 1);
    MEMFENCE();

    f32x4 acc0[8], acc1[8];
#pragma unroll
    for (int t = 0; t < 8; t++) {
        acc0[t] = (f32x4){0.f, 0.f, 0.f, 0.f};
        acc1[t] = (f32x4){0.f, 0.f, 0.f, 0.f};
    }

    bf16x8 af0, af1;
#pragma unroll
    for (int u = 0; u < 16; u++) {
        // unit u landed (this wave); barrier makes it collective.
        if (u == 0 || u == 15) asm volatile("s_waitcnt vmcnt(0)" ::: "memory");
        else                   asm volatile("s_waitcnt vmcnt(4)" ::: "memory");
        __builtin_amdgcn_s_barrier();
        if ((u & 1) == 0) {               // new ks: read A fragments (swizzled)
            int co = (quad * 16 + (u >> 1) * 64) ^ sw;
            af0 = *(const bf16x8*)((const char*)A_lds + m * 512 + co);
            af1 = *(const bf16x8*)((const char*)A_lds + (m + 16) * 512 + co);
        }
        const char* Bb = (const char*)(&B_lds[u & 1][0])
                       + ((size_t)(wave * 4) * 64 + lane) * 16;
        bf16x8 b0 = *(const bf16x8*)(Bb);
        bf16x8 b1 = *(const bf16x8*)(Bb + 1024);
        bf16x8 b2 = *(const bf16x8*)(Bb + 2048);
        bf16x8 b3 = *(const bf16x8*)(Bb + 3072);
        asm volatile("s_waitcnt lgkmcnt(0)" ::: "memory");  // reads retired
        __builtin_amdgcn_s_barrier();                       // all waves done w/ buf
        if (u < 14) stage_unit(u + 2, u & 1);               // overwrite is now safe
        MEMFENCE();
        int t0 = (u & 1) * 4;
        __builtin_amdgcn_s_setprio(1);
        acc0[t0 + 0] = __builtin_amdgcn_mfma_f32_16x16x32_bf16(af0, b0, acc0[t0 + 0], 0, 0, 0);
        acc1[t0 + 0] = __builtin_amdgcn_mfma_f32_16x16x32_bf16(af1, b0, acc1[t0 + 0], 0, 0, 0);
        acc0[t0 + 1] = __builtin_amdgcn_mfma_f32_16x16x32_bf16(af0, b1, acc0[t0 + 1], 0, 0, 0);
        acc1[t0 + 1] = __builtin_amdgcn_mfma_f32_16x16x32_bf16(af1, b1, acc1[t0 + 1], 0, 0, 0);
        acc0[t0 + 2] = __builtin_amdgcn_mfma_f32_16x16x32_bf16(af0, b2, acc0[t0 + 2], 0, 0, 0);
        acc1[t0 + 2] = __builtin_amdgcn_mfma_f32_16x16x32_bf16(af1, b2, acc1[t0 + 2], 0, 0, 0);
        acc0[t0 + 3] = __builtin_amdgcn_mfma_f32_16x16x32_bf16(af0, b3, acc0[t0 + 3], 0, 0, 0);
        acc1[t0 + 3] = __builtin_amdgcn_mfma_f32_16x16x32_bf16(af1, b3, acc1[t0 + 3], 0, 0, 0);
        __builtin_amdgcn_s_setprio(0);
    }

    // bias (col = (wave*8+t)*16 + m)
#pragma unroll
    for (int t = 0; t < 8; t++) {
        float bb = bias[(wave * 8 + t) * 16 + m];
        acc0[t][0] += bb; acc0[t][1] += bb; acc0[t][2] += bb; acc0[t][3] += bb;
        acc1[t][0] += bb; acc1[t][1] += bb; acc1[t][2] += bb; acc1[t][3] += bb;
    }

    // ---- row max ----
    float mx0[4], mx1[4];
#pragma unroll
    for (int r = 0; r < 4; r++) {
        float v0 = acc0[0][r], v1 = acc1[0][r];
#pragma unroll
        for (int t = 1; t < 8; t++) { v0 = fmaxf(v0, acc0[t][r]); v1 = fmaxf(v1, acc1[t][r]); }
        mx0[r] = v0; mx1[r] = v1;
    }
#pragma unroll
    for (int off = 1; off < 16; off <<= 1)
#pragma unroll
        for (int r = 0; r < 4; r++) {
            mx0[r] = fmaxf(mx0[r], __shfl_xor(mx0[r], off));
            mx1[r] = fmaxf(mx1[r], __shfl_xor(mx1[r], off));
        }
    if (m == 0)
#pragma unroll
        for (int r = 0; r < 4; r++) {
            sred[quad * 4 + r][wave]      = mx0[r];
            sred[16 + quad * 4 + r][wave] = mx1[r];
        }
    __syncthreads();
    if (tid < 32) {
        float v = sred[tid][0];
#pragma unroll
        for (int w = 1; w < 16; w++) v = fmaxf(v, sred[tid][w]);
        sfinm[tid] = v;
    }
    __syncthreads();
#pragma unroll
    for (int r = 0; r < 4; r++) { mx0[r] = sfinm[quad * 4 + r]; mx1[r] = sfinm[16 + quad * 4 + r]; }

    // ---- exp + row sum ----
    float ls0[4] = {0.f, 0.f, 0.f, 0.f}, ls1[4] = {0.f, 0.f, 0.f, 0.f};
#pragma unroll
    for (int t = 0; t < 8; t++) {
#pragma unroll
        for (int r = 0; r < 4; r++) {
            float e0 = __expf(acc0[t][r] - mx0[r]);
            float e1 = __expf(acc1[t][r] - mx1[r]);
            acc0[t][r] = e0; acc1[t][r] = e1;
            ls0[r] += e0; ls1[r] += e1;
        }
    }
#pragma unroll
    for (int off = 1; off < 16; off <<= 1)
#pragma unroll
        for (int r = 0; r < 4; r++) {
            ls0[r] += __shfl_xor(ls0[r], off);
            ls1[r] += __shfl_xor(ls1[r], off);
        }
    if (m == 0)
#pragma unroll
        for (int r = 0; r < 4; r++) {
            sred[quad * 4 + r][wave]      = ls0[r];
            sred[16 + quad * 4 + r][wave] = ls1[r];
        }
    __syncthreads();
    if (tid < 32) {
        float v = 0.f;
#pragma unroll
        for (int w = 0; w < 16; w++) v += sred[tid][w];
        sfinl[tid] = v;
    }
    __syncthreads();

    float rinv0[4], rinv1[4];
#pragma unroll
    for (int r = 0; r < 4; r++) {
        int ra = quad * 4 + r, rb = 16 + quad * 4 + r;
        rinv0[r] = (row0 + ra < N_NODES) ? 1.0f / sfinl[ra] : 0.0f;
        rinv1[r] = (row0 + rb < N_NODES) ? 1.0f / sfinl[rb] : 0.0f;
    }

    // ---- column sums over 32 rows -> atomics into replica ----
    float* dst = fp_part + (size_t)(blockIdx.x & 31) * OUT_DIM;
#pragma unroll
    for (int t = 0; t < 8; t++) {
        float cs = acc0[t][0] * rinv0[0] + acc0[t][1] * rinv0[1]
                 + acc0[t][2] * rinv0[2] + acc0[t][3] * rinv0[3]
                 + acc1[t][0] * rinv1[0] + acc1[t][1] * rinv1[1]
                 + acc1[t][2] * rinv1[2] + acc1[t][3] * rinv1[3];
        cs += __shfl_xor(cs, 16);
        cs += __shfl_xor(cs, 32);
        if (quad == 0)
            atomicAdd(&dst[(wave * 8 + t) * 16 + m], cs);
    }
}

// ---------------------------------------------------------------------------
__global__ void k_fp_reduce(const float* __restrict__ part, float* __restrict__ fp) {
    int c = blockIdx.x * 256 + threadIdx.x;   // 2048
    float s = 0.f;
#pragma unroll
    for (int r = 0; r < 32; r++) s += part[(size_t)r * OUT_DIM + c];
    fp[c] = s;
}

// ---------------------------------------------------------------------------
extern "C" void kernel_launch(void* const* d_in, const int* in_sizes, int n_in,
                              void* d_out, int out_size, void* d_ws, size_t ws_size,
                              hipStream_t stream) {
    const float* node_attr = (const float*)d_in[0];
    const float* edge_attr = (const float*)d_in[1];
    const int*   edge_src  = (const int*)d_in[2];
    const int*   edge_dst  = (const int*)d_in[3];
    const float* W_inner   = (const float*)d_in[4];
    const float* b_inner   = (const float*)d_in[5];
    const float* W_output  = (const float*)d_in[6];
    const float* b_output  = (const float*)d_in[7];

    float* fp      = (float*)d_out;
    float* attr    = (float*)d_ws;                        // N*256 f32
    float* agg     = attr + (size_t)N_NODES * DIM;        // N*256 f32
    float* fp_part = agg + (size_t)N_NODES * DIM;         // 32*2048 f32
    short* Wz      = (short*)(fp_part + 32 * OUT_DIM);    // 4*2^16*8 bf16 frags (4 MB)
    int*   deg     = (int*)(Wz + (size_t)4 * 65536 * 8);  // N
    int*   rowptr  = deg + N_NODES;                       // N+1 (+3 pad for alignment)
    int*   eidx    = rowptr + N_NODES + 4;                // M   (pad keeps esum/attr_bf 16B-aligned)
    int*   srcs    = eidx + M_EDGES;                      // M
    float* esum    = (float*)(srcs + M_EDGES);            // N*64 f32 (12.8 MB), 16B-aligned
    short* attr_bf = (short*)(esum + (size_t)N_NODES * EDGE_F); // N_PAD*256 bf16, 16B-aligned

    hipMemsetAsync(fp_part, 0, 32 * OUT_DIM * sizeof(float), stream);
    hipMemsetAsync(deg, 0, N_NODES * sizeof(int), stream);

    k_init_attr<<<(N_PAD * 64 + 255) / 256, 256, 0, stream>>>(node_attr, attr, attr_bf);

    // CSR build (once, reused for all depths)
    k_degree<<<(M_EDGES + 255) / 256, 256, 0, stream>>>(edge_dst, deg);
    k_scan<<<1, 1024, 0, stream>>>(deg, rowptr);
    k_fill<<<(M_EDGES + 255) / 256, 256, 0, stream>>>(edge_dst, edge_src, deg, eidx, srcs);
    k_esum<<<(N_NODES * 16 + 255) / 256, 256, 0, stream>>>(edge_attr, rowptr, eidx, esum);

    // W_output -> bf16 fragment swizzle (all 4 depths, unit-major layout)
    k_wswz<<<1024, 256, 0, stream>>>(W_output, Wz);

    k_fp_mfma<<<N_PAD / 32, 1024, 0, stream>>>(attr_bf, Wz, b_output, fp_part);

    for (int d = 1; d <= DEPTH; d++) {
        k_gather<<<(N_NODES * 64 + 255) / 256, 256, 0, stream>>>(
            attr, rowptr, srcs, esum, agg);
        k_inner<<<(N_NODES + 31) / 32, 256, 0, stream>>>(
            attr, agg, W_inner + (size_t)(d - 1) * DIM * DIM,
            b_inner + (size_t)(d - 1) * DIM, attr, attr_bf);
        k_fp_mfma<<<N_PAD / 32, 1024, 0, stream>>>(
            attr_bf, Wz + (size_t)d * 65536 * 8,
            b_output + (size_t)d * OUT_DIM, fp_part);
    }
    k_fp_reduce<<<OUT_DIM / 256, 256, 0, stream>>>(fp_part, fp);
}

// Round 3
// 1758.162 us; speedup vs baseline: 1.0617x; 1.0056x over previous
//
#include <hip/hip_runtime.h>
#include <hip/hip_bf16.h>

#define N_NODES 50000
#define N_PAD   50016          // padded to 32-row blocks for k_fp_mfma
#define NODE_F  192
#define EDGE_F  64
#define DIM     256
#define OUT_DIM 2048
#define DEPTH   3
#define M_EDGES 800000

typedef short  bf16x8 __attribute__((ext_vector_type(8)));   // 8 bf16 in 4 VGPRs
typedef float  f32x4  __attribute__((ext_vector_type(4)));

__device__ inline short f2bf(float f) {
    unsigned u = __float_as_uint(f);
    unsigned r = (u + 0x7fffu + ((u >> 16) & 1u)) >> 16;
    return (short)r;
}

// async global->LDS, 16B per lane; LDS dest is wave-uniform base + lane*16
#define GLDS16(g, l) __builtin_amdgcn_global_load_lds(                        \
    (const __attribute__((address_space(1))) void*)(g),                       \
    (__attribute__((address_space(3))) void*)(l), 16, 0, 0)

#define MEMFENCE() asm volatile("" ::: "memory")

// ---------------------------------------------------------------------------
// attr = [node_attr | zeros(EDGE_F)] -> [N,256] fp32, plus bf16 mirror
// ---------------------------------------------------------------------------
__global__ void k_init_attr(const float* __restrict__ node_attr,
                            float* __restrict__ attr,
                            short* __restrict__ attr_bf) {
    int i = blockIdx.x * 256 + threadIdx.x;   // float4/short4 slot over N_PAD*64
    int row = i >> 6, q = i & 63;
    if (row >= N_PAD) return;
    float4 v = make_float4(0.f, 0.f, 0.f, 0.f);
    if (row < N_NODES && q < NODE_F / 4)
        v = ((const float4*)node_attr)[row * (NODE_F / 4) + q];
    if (row < N_NODES) ((float4*)attr)[i] = v;
    short4 s; s.x = f2bf(v.x); s.y = f2bf(v.y); s.z = f2bf(v.z); s.w = f2bf(v.w);
    ((short4*)attr_bf)[i] = s;
}

// ---------------------------------------------------------------------------
// CSR build: degree histogram -> single-block scan -> edge-index fill
// ---------------------------------------------------------------------------
__global__ void k_degree(const int* __restrict__ dst, int* __restrict__ deg) {
    int e = blockIdx.x * 256 + threadIdx.x;
    if (e < M_EDGES) atomicAdd(&deg[dst[e]], 1);
}

__global__ __launch_bounds__(1024) void k_scan(int* __restrict__ deg,
                                               int* __restrict__ rowptr) {
    __shared__ int part[1024];
    int t = threadIdx.x;
    const int CH = (N_NODES + 1023) / 1024;   // 49
    int beg = t * CH, end = min(beg + CH, N_NODES);
    int s = 0;
    for (int i = beg; i < end; i++) s += deg[i];
    part[t] = s;
    __syncthreads();
    for (int off = 1; off < 1024; off <<= 1) {
        int v = (t >= off) ? part[t - off] : 0;
        __syncthreads();
        part[t] += v;
        __syncthreads();
    }
    int run = (t == 0) ? 0 : part[t - 1];
    for (int i = beg; i < end; i++) {
        int d = deg[i];
        rowptr[i] = run;
        deg[i] = run;      // cursor for k_fill
        run += d;
    }
    if (t == 1023) rowptr[N_NODES] = run;
}

// fill: eidx (edge id, dst-sorted) and srcs (source node, dst-sorted)
__global__ void k_fill(const int* __restrict__ dst, const int* __restrict__ src,
                       int* __restrict__ cursor,
                       int* __restrict__ eidx, int* __restrict__ srcs) {
    int e = blockIdx.x * 256 + threadIdx.x;
    if (e < M_EDGES) {
        int p = atomicAdd(&cursor[dst[e]], 1);
        eidx[p] = e;
        srcs[p] = src[e];
    }
}

// ---------------------------------------------------------------------------
// esum[i] = sum_{e : dst[e]==i} edge_attr[e]   (depth-invariant, [N,64] f32)
// 16 threads per node, one float4 lane each.
// ---------------------------------------------------------------------------
__global__ __launch_bounds__(256) void k_esum(const float* __restrict__ edge_attr,
                                              const int* __restrict__ rowptr,
                                              const int* __restrict__ eidx,
                                              float* __restrict__ esum) {
    int gid = blockIdx.x * 256 + threadIdx.x;   // over N*16
    int node = gid >> 4, q = gid & 15;
    if (node >= N_NODES) return;
    int beg = rowptr[node], end = rowptr[node + 1];
    float4 acc = make_float4(0.f, 0.f, 0.f, 0.f);
    const float4* E4 = (const float4*)edge_attr;
    for (int i = beg; i < end; i++) {
        int e = eidx[i];
        float4 v = E4[(size_t)e * 16 + q];
        acc.x += v.x; acc.y += v.y; acc.z += v.z; acc.w += v.w;
    }
    ((float4*)esum)[(size_t)node * 16 + q] = acc;
}

// ---------------------------------------------------------------------------
// gather: agg[i] = esum_pad[i] + sum_{e : dst[e]==i} attr[srcs]
// one wave (64 lanes x float4) per node; srcs is dst-sorted (sequential).
// ---------------------------------------------------------------------------
__global__ __launch_bounds__(256) void k_gather(const float* __restrict__ attr,
                                                const int* __restrict__ rowptr,
                                                const int* __restrict__ srcs,
                                                const float* __restrict__ esum,
                                                float* __restrict__ agg) {
    int gid = blockIdx.x * 256 + threadIdx.x;
    int node = gid >> 6, q = gid & 63;
    if (node >= N_NODES) return;
    int beg = rowptr[node], end = rowptr[node + 1];
    float4 acc = make_float4(0.f, 0.f, 0.f, 0.f);
    if (q >= NODE_F / 4)
        acc = ((const float4*)esum)[(size_t)node * 16 + (q - NODE_F / 4)];
    const float4* A4 = (const float4*)attr;
    for (int i = beg; i < end; i++) {
        int s = srcs[i];                 // wave-uniform sequential load
        float4 v = A4[(size_t)s * 64 + q];
        acc.x += v.x; acc.y += v.y; acc.z += v.z; acc.w += v.w;
    }
    ((float4*)agg)[(size_t)node * 64 + q] = acc;
}

// ---------------------------------------------------------------------------
// inner GEMM: attr_new = (attr + agg) @ W + b, in-place on attr (fp32 vector),
// also writes the bf16 mirror used by k_fp_mfma.
// ---------------------------------------------------------------------------
__global__ __launch_bounds__(256) void k_inner(const float* __restrict__ attr,
                                               const float* __restrict__ agg,
                                               const float* __restrict__ W,
                                               const float* __restrict__ b,
                                               float* __restrict__ out,
                                               short* __restrict__ out_bf) {
    __shared__ float4 sV[32][64];   // 32 KB
    int tid  = threadIdx.x;
    int row0 = blockIdx.x * 32;

    for (int i = tid; i < 32 * 64; i += 256) {
        int r = i >> 6, q = i & 63;
        int grow = row0 + r;
        float4 v = make_float4(0.f, 0.f, 0.f, 0.f);
        if (grow < N_NODES) {
            float4 a = ((const float4*)attr)[(size_t)grow * 64 + q];
            float4 g = ((const float4*)agg)[(size_t)grow * 64 + q];
            v = make_float4(a.x + g.x, a.y + g.y, a.z + g.z, a.w + g.w);
        }
        sV[r][q] = v;
    }
    __syncthreads();

    int cg = tid & 63;
    int rg = tid >> 6;

    float4 acc[8];
#pragma unroll
    for (int r = 0; r < 8; r++) acc[r] = make_float4(0.f, 0.f, 0.f, 0.f);

    const float4* W4 = (const float4*)W;
    for (int k4 = 0; k4 < 64; k4++) {
        float4 w0 = W4[(size_t)(k4 * 4 + 0) * 64 + cg];
        float4 w1 = W4[(size_t)(k4 * 4 + 1) * 64 + cg];
        float4 w2 = W4[(size_t)(k4 * 4 + 2) * 64 + cg];
        float4 w3 = W4[(size_t)(k4 * 4 + 3) * 64 + cg];
#pragma unroll
        for (int r = 0; r < 8; r++) {
            float4 a = sV[rg * 8 + r][k4];
            acc[r].x += a.x * w0.x + a.y * w1.x + a.z * w2.x + a.w * w3.x;
            acc[r].y += a.x * w0.y + a.y * w1.y + a.z * w2.y + a.w * w3.y;
            acc[r].z += a.x * w0.z + a.y * w1.z + a.z * w2.z + a.w * w3.z;
            acc[r].w += a.x * w0.w + a.y * w1.w + a.z * w2.w + a.w * w3.w;
        }
    }

    float4 bb = ((const float4*)b)[cg];
#pragma unroll
    for (int r = 0; r < 8; r++) {
        int grow = row0 + rg * 8 + r;
        if (grow < N_NODES) {
            float4 o = make_float4(acc[r].x + bb.x, acc[r].y + bb.y,
                                   acc[r].z + bb.z, acc[r].w + bb.w);
            ((float4*)out)[(size_t)grow * 64 + cg] = o;
            short4 s; s.x = f2bf(o.x); s.y = f2bf(o.y); s.z = f2bf(o.z); s.w = f2bf(o.w);
            ((short4*)out_bf)[(size_t)grow * 64 + cg] = s;
        }
    }
}

// ---------------------------------------------------------------------------
// W_output swizzle: fp32 [4][256][2048] -> bf16 fragment layout, UNIT-MAJOR:
// unit uu = ks*2 + h (h = t>>2) is a contiguous 64 KB block of fragments
// ordered [w][j=t&3][lane], so k_fp_mfma can stage one unit with linear
// global_load_lds.
// ---------------------------------------------------------------------------
__global__ void k_wswz(const float* __restrict__ W, short* __restrict__ Wz) {
    int idx = blockIdx.x * 256 + threadIdx.x;    // 2^18 total
    int lane = idx & 63;
    int T    = (idx >> 6) & 127;
    int ks   = (idx >> 13) & 7;
    int d    = idx >> 16;
    int quad = lane >> 4;
    int m    = lane & 15;
    const float* src = W + ((size_t)(d * 256 + ks * 32 + quad * 8)) * 2048 + T * 16 + m;
    int w = T >> 3, h = (T >> 2) & 1, j = T & 3;
    size_t n = ((((size_t)(ks * 2 + h)) * 16 + w) * 4 + j) * 64 + lane;
    short* dstp = Wz + ((size_t)d * 65536 + n) * 8;
#pragma unroll
    for (int jj = 0; jj < 8; jj++) dstp[jj] = f2bf(src[(size_t)jj * 2048]);
}

// ---------------------------------------------------------------------------
// fp contribution via MFMA: fp_part += colsum(softmax(attr @ W + b))
// 32 rows/block, 1024 thr = 16 waves; wave = 32 rows x 128 cols.
// C/D layout: col = lane&15, row = (lane>>4)*4 + reg.
//
// Schedule (T2+T3+T4+T5) + L2 anti-camping stagger:
//  - all blocks used to sweep units 0..15 in lockstep, so every CU on an XCD
//    camped on the same 64 KB of Wz at once -> effective delivery ~17 B/cy/CU
//    (3x below fair L2 share; measured 3700 cy/phase vs ~1200 ideal).
//    K-accumulation is commutative, so each block now starts its unit sweep
//    at an even offset derived from blockIdx -> concurrent CUs read 8
//    different 64 KB regions. Even offsets keep the ks/A-fragment cadence
//    and the buffer parity identical to the verified schedule.
//  - counted vmcnt(4) + raw s_barrier per phase, vmcnt(0) only at p=0/15.
// ---------------------------------------------------------------------------
__global__ __launch_bounds__(1024)
void k_fp_mfma(const short* __restrict__ attr_bf,
               const short* __restrict__ Wz,    // depth offset applied by host
               const float* __restrict__ bias,
               float* __restrict__ fp_part) {
    __shared__ __align__(16) short A_lds[32 * 256];      // 16 KB (swizzled)
    __shared__ __align__(16) short B_lds[2][4096 * 8];   // 2 x 64 KB units
    __shared__ float sred[32][17];
    __shared__ float sfinm[32];
    __shared__ float sfinl[32];
    int tid  = threadIdx.x;
    int lane = tid & 63;
    int wave = tid >> 6;          // 0..15
    int quad = lane >> 4;
    int m    = lane & 15;
    int row0 = blockIdx.x * 32;
    int sw   = (m & 7) << 4;      // A-tile XOR swizzle term
    int start = ((blockIdx.x >> 3) & 7) << 1;   // even unit-sweep offset

    // ---- prologue: stage A tile (swizzled source) + units start,start+1 ----
    {
        int r   = tid >> 5;               // row 0..31
        int c16 = tid & 31;               // 16B slot in row
        const char* gsrc = (const char*)attr_bf
            + (size_t)(row0 + r) * 512 + (size_t)((c16 * 16) ^ ((r & 7) << 4));
        char* ldst = (char*)A_lds + (size_t)wave * 1024;   // + lane*16 by HW
        GLDS16(gsrc, ldst);
    }
    MEMFENCE();
    auto stage_unit = [&](int uu, int b) {
        const char* gb = (const char*)Wz + (size_t)uu * 65536 + (size_t)tid * 16;
        char* lb = (char*)(&B_lds[b][0]) + wave * 1024;    // + lane*16 by HW
#pragma unroll
        for (int p = 0; p < 4; p++)
            GLDS16(gb + p * 16384, lb + p * 16384);
    };
    stage_unit(start, 0);
    MEMFENCE();
    stage_unit((start + 1) & 15, 1);
    MEMFENCE();

    f32x4 acc0[8], acc1[8];
#pragma unroll
    for (int t = 0; t < 8; t++) {
        acc0[t] = (f32x4){0.f, 0.f, 0.f, 0.f};
        acc1[t] = (f32x4){0.f, 0.f, 0.f, 0.f};
    }

    bf16x8 af0, af1;
#pragma unroll
    for (int p = 0; p < 16; p++) {
        int u = (start + p) & 15;         // unit processed this phase
        // unit u landed (this wave); barrier makes it collective.
        if (p == 0 || p == 15) asm volatile("s_waitcnt vmcnt(0)" ::: "memory");
        else                   asm volatile("s_waitcnt vmcnt(4)" ::: "memory");
        __builtin_amdgcn_s_barrier();
        if ((p & 1) == 0) {               // new ks (start even): read A frags
            int ks = u >> 1;
            int co = (quad * 16 + ks * 64) ^ sw;
            af0 = *(const bf16x8*)((const char*)A_lds + m * 512 + co);
            af1 = *(const bf16x8*)((const char*)A_lds + (m + 16) * 512 + co);
        }
        const char* Bb = (const char*)(&B_lds[p & 1][0])
                       + ((size_t)(wave * 4) * 64 + lane) * 16;
        bf16x8 b0 = *(const bf16x8*)(Bb);
        bf16x8 b1 = *(const bf16x8*)(Bb + 1024);
        bf16x8 b2 = *(const bf16x8*)(Bb + 2048);
        bf16x8 b3 = *(const bf16x8*)(Bb + 3072);
        asm volatile("s_waitcnt lgkmcnt(0)" ::: "memory");  // reads retired
        __builtin_amdgcn_s_barrier();                       // all waves done w/ buf
        if (p < 14) stage_unit((start + p + 2) & 15, p & 1);
        MEMFENCE();
        int t0 = (u & 1) * 4;             // acc half keyed to UNIT, not phase
        __builtin_amdgcn_s_setprio(1);
        acc0[t0 + 0] = __builtin_amdgcn_mfma_f32_16x16x32_bf16(af0, b0, acc0[t0 + 0], 0, 0, 0);
        acc1[t0 + 0] = __builtin_amdgcn_mfma_f32_16x16x32_bf16(af1, b0, acc1[t0 + 0], 0, 0, 0);
        acc0[t0 + 1] = __builtin_amdgcn_mfma_f32_16x16x32_bf16(af0, b1, acc0[t0 + 1], 0, 0, 0);
        acc1[t0 + 1] = __builtin_amdgcn_mfma_f32_16x16x32_bf16(af1, b1, acc1[t0 + 1], 0, 0, 0);
        acc0[t0 + 2] = __builtin_amdgcn_mfma_f32_16x16x32_bf16(af0, b2, acc0[t0 + 2], 0, 0, 0);
        acc1[t0 + 2] = __builtin_amdgcn_mfma_f32_16x16x32_bf16(af1, b2, acc1[t0 + 2], 0, 0, 0);
        acc0[t0 + 3] = __builtin_amdgcn_mfma_f32_16x16x32_bf16(af0, b3, acc0[t0 + 3], 0, 0, 0);
        acc1[t0 + 3] = __builtin_amdgcn_mfma_f32_16x16x32_bf16(af1, b3, acc1[t0 + 3], 0, 0, 0);
        __builtin_amdgcn_s_setprio(0);
    }

    // bias (col = (wave*8+t)*16 + m)
#pragma unroll
    for (int t = 0; t < 8; t++) {
        float bb = bias[(wave * 8 + t) * 16 + m];
        acc0[t][0] += bb; acc0[t][1] += bb; acc0[t][2] += bb; acc0[t][3] += bb;
        acc1[t][0] += bb; acc1[t][1] += bb; acc1[t][2] += bb; acc1[t][3] += bb;
    }

    // ---- row max ----
    float mx0[4], mx1[4];
#pragma unroll
    for (int r = 0; r < 4; r++) {
        float v0 = acc0[0][r], v1 = acc1[0][r];
#pragma unroll
        for (int t = 1; t < 8; t++) { v0 = fmaxf(v0, acc0[t][r]); v1 = fmaxf(v1, acc1[t][r]); }
        mx0[r] = v0; mx1[r] = v1;
    }
#pragma unroll
    for (int off = 1; off < 16; off <<= 1)
#pragma unroll
        for (int r = 0; r < 4; r++) {
            mx0[r] = fmaxf(mx0[r], __shfl_xor(mx0[r], off));
            mx1[r] = fmaxf(mx1[r], __shfl_xor(mx1[r], off));
        }
    if (m == 0)
#pragma unroll
        for (int r = 0; r < 4; r++) {
            sred[quad * 4 + r][wave]      = mx0[r];
            sred[16 + quad * 4 + r][wave] = mx1[r];
        }
    __syncthreads();
    if (tid < 32) {
        float v = sred[tid][0];
#pragma unroll
        for (int w = 1; w < 16; w++) v = fmaxf(v, sred[tid][w]);
        sfinm[tid] = v;
    }
    __syncthreads();
#pragma unroll
    for (int r = 0; r < 4; r++) { mx0[r] = sfinm[quad * 4 + r]; mx1[r] = sfinm[16 + quad * 4 + r]; }

    // ---- exp + row sum ----
    float ls0[4] = {0.f, 0.f, 0.f, 0.f}, ls1[4] = {0.f, 0.f, 0.f, 0.f};
#pragma unroll
    for (int t = 0; t < 8; t++) {
#pragma unroll
        for (int r = 0; r < 4; r++) {
            float e0 = __expf(acc0[t][r] - mx0[r]);
            float e1 = __expf(acc1[t][r] - mx1[r]);
            acc0[t][r] = e0; acc1[t][r] = e1;
            ls0[r] += e0; ls1[r] += e1;
        }
    }
#pragma unroll
    for (int off = 1; off < 16; off <<= 1)
#pragma unroll
        for (int r = 0; r < 4; r++) {
            ls0[r] += __shfl_xor(ls0[r], off);
            ls1[r] += __shfl_xor(ls1[r], off);
        }
    if (m == 0)
#pragma unroll
        for (int r = 0; r < 4; r++) {
            sred[quad * 4 + r][wave]      = ls0[r];
            sred[16 + quad * 4 + r][wave] = ls1[r];
        }
    __syncthreads();
    if (tid < 32) {
        float v = 0.f;
#pragma unroll
        for (int w = 0; w < 16; w++) v += sred[tid][w];
        sfinl[tid] = v;
    }
    __syncthreads();

    float rinv0[4], rinv1[4];
#pragma unroll
    for (int r = 0; r < 4; r++) {
        int ra = quad * 4 + r, rb = 16 + quad * 4 + r;
        rinv0[r] = (row0 + ra < N_NODES) ? 1.0f / sfinl[ra] : 0.0f;
        rinv1[r] = (row0 + rb < N_NODES) ? 1.0f / sfinl[rb] : 0.0f;
    }

    // ---- column sums over 32 rows -> atomics into replica ----
    float* dst = fp_part + (size_t)(blockIdx.x & 31) * OUT_DIM;
#pragma unroll
    for (int t = 0; t < 8; t++) {
        float cs = acc0[t][0] * rinv0[0] + acc0[t][1] * rinv0[1]
                 + acc0[t][2] * rinv0[2] + acc0[t][3] * rinv0[3]
                 + acc1[t][0] * rinv1[0] + acc1[t][1] * rinv1[1]
                 + acc1[t][2] * rinv1[2] + acc1[t][3] * rinv1[3];
        cs += __shfl_xor(cs, 16);
        cs += __shfl_xor(cs, 32);
        if (quad == 0)
            atomicAdd(&dst[(wave * 8 + t) * 16 + m], cs);
    }
}

// ---------------------------------------------------------------------------
__global__ void k_fp_reduce(const float* __restrict__ part, float* __restrict__ fp) {
    int c = blockIdx.x * 256 + threadIdx.x;   // 2048
    float s = 0.f;
#pragma unroll
    for (int r = 0; r < 32; r++) s += part[(size_t)r * OUT_DIM + c];
    fp[c] = s;
}

// ---------------------------------------------------------------------------
extern "C" void kernel_launch(void* const* d_in, const int* in_sizes, int n_in,
                              void* d_out, int out_size, void* d_ws, size_t ws_size,
                              hipStream_t stream) {
    const float* node_attr = (const float*)d_in[0];
    const float* edge_attr = (const float*)d_in[1];
    const int*   edge_src  = (const int*)d_in[2];
    const int*   edge_dst  = (const int*)d_in[3];
    const float* W_inner   = (const float*)d_in[4];
    const float* b_inner   = (const float*)d_in[5];
    const float* W_output  = (const float*)d_in[6];
    const float* b_output  = (const float*)d_in[7];

    float* fp      = (float*)d_out;
    float* attr    = (float*)d_ws;                        // N*256 f32
    float* agg     = attr + (size_t)N_NODES * DIM;        // N*256 f32
    float* fp_part = agg + (size_t)N_NODES * DIM;         // 32*2048 f32
    short* Wz      = (short*)(fp_part + 32 * OUT_DIM);    // 4*2^16*8 bf16 frags (4 MB)
    int*   deg     = (int*)(Wz + (size_t)4 * 65536 * 8);  // N
    int*   rowptr  = deg + N_NODES;                       // N+1 (+3 pad for alignment)
    int*   eidx    = rowptr + N_NODES + 4;                // M   (pad keeps esum/attr_bf 16B-aligned)
    int*   srcs    = eidx + M_EDGES;                      // M
    float* esum    = (float*)(srcs + M_EDGES);            // N*64 f32 (12.8 MB), 16B-aligned
    short* attr_bf = (short*)(esum + (size_t)N_NODES * EDGE_F); // N_PAD*256 bf16, 16B-aligned

    hipMemsetAsync(fp_part, 0, 32 * OUT_DIM * sizeof(float), stream);
    hipMemsetAsync(deg, 0, N_NODES * sizeof(int), stream);

    k_init_attr<<<(N_PAD * 64 + 255) / 256, 256, 0, stream>>>(node_attr, attr, attr_bf);

    // CSR build (once, reused for all depths)
    k_degree<<<(M_EDGES + 255) / 256, 256, 0, stream>>>(edge_dst, deg);
    k_scan<<<1, 1024, 0, stream>>>(deg, rowptr);
    k_fill<<<(M_EDGES + 255) / 256, 256, 0, stream>>>(edge_dst, edge_src, deg, eidx, srcs);
    k_esum<<<(N_NODES * 16 + 255) / 256, 256, 0, stream>>>(edge_attr, rowptr, eidx, esum);

    // W_output -> bf16 fragment swizzle (all 4 depths, unit-major layout)
    k_wswz<<<1024, 256, 0, stream>>>(W_output, Wz);

    k_fp_mfma<<<N_PAD / 32, 1024, 0, stream>>>(attr_bf, Wz, b_output, fp_part);

    for (int d = 1; d <= DEPTH; d++) {
        k_gather<<<(N_NODES * 64 + 255) / 256, 256, 0, stream>>>(
            attr, rowptr, srcs, esum, agg);
        k_inner<<<(N_NODES + 31) / 32, 256, 0, stream>>>(
            attr, agg, W_inner + (size_t)(d - 1) * DIM * DIM,
            b_inner + (size_t)(d - 1) * DIM, attr, attr_bf);
        k_fp_mfma<<<N_PAD / 32, 1024, 0, stream>>>(
            attr_bf, Wz + (size_t)d * 65536 * 8,
            b_output + (size_t)d * OUT_DIM, fp_part);
    }
    k_fp_reduce<<<OUT_DIM / 256, 256, 0, stream>>>(fp_part, fp);
}

// Round 4
// 1711.225 us; speedup vs baseline: 1.0908x; 1.0274x over previous
//
#include <hip/hip_runtime.h>
#include <hip/hip_bf16.h>

#define N_NODES 50000
#define N_PAD   50016          // padded to 32-row blocks for k_fp_mfma
#define NODE_F  192
#define EDGE_F  64
#define DIM     256
#define OUT_DIM 2048
#define DEPTH   3
#define M_EDGES 800000

typedef short  bf16x8 __attribute__((ext_vector_type(8)));   // 8 bf16 in 4 VGPRs
typedef float  f32x4  __attribute__((ext_vector_type(4)));

__device__ inline short f2bf(float f) {
    unsigned u = __float_as_uint(f);
    unsigned r = (u + 0x7fffu + ((u >> 16) & 1u)) >> 16;
    return (short)r;
}

// async global->LDS, 16B per lane; LDS dest is wave-uniform base + lane*16
#define GLDS16(g, l) __builtin_amdgcn_global_load_lds(                        \
    (const __attribute__((address_space(1))) void*)(g),                       \
    (__attribute__((address_space(3))) void*)(l), 16, 0, 0)

#define MFMA16(a, b, c) __builtin_amdgcn_mfma_f32_16x16x32_bf16((a), (b), (c), 0, 0, 0)

// ---------------------------------------------------------------------------
// attr = [node_attr | zeros(EDGE_F)] -> [N,256] fp32, plus bf16 mirror
// ---------------------------------------------------------------------------
__global__ void k_init_attr(const float* __restrict__ node_attr,
                            float* __restrict__ attr,
                            short* __restrict__ attr_bf) {
    int i = blockIdx.x * 256 + threadIdx.x;   // float4/short4 slot over N_PAD*64
    int row = i >> 6, q = i & 63;
    if (row >= N_PAD) return;
    float4 v = make_float4(0.f, 0.f, 0.f, 0.f);
    if (row < N_NODES && q < NODE_F / 4)
        v = ((const float4*)node_attr)[row * (NODE_F / 4) + q];
    if (row < N_NODES) ((float4*)attr)[i] = v;
    short4 s; s.x = f2bf(v.x); s.y = f2bf(v.y); s.z = f2bf(v.z); s.w = f2bf(v.w);
    ((short4*)attr_bf)[i] = s;
}

// ---------------------------------------------------------------------------
// CSR build: degree histogram -> single-block scan -> edge-index fill
// ---------------------------------------------------------------------------
__global__ void k_degree(const int* __restrict__ dst, int* __restrict__ deg) {
    int e = blockIdx.x * 256 + threadIdx.x;
    if (e < M_EDGES) atomicAdd(&deg[dst[e]], 1);
}

__global__ __launch_bounds__(1024) void k_scan(int* __restrict__ deg,
                                               int* __restrict__ rowptr) {
    __shared__ int part[1024];
    int t = threadIdx.x;
    const int CH = (N_NODES + 1023) / 1024;   // 49
    int beg = t * CH, end = min(beg + CH, N_NODES);
    int s = 0;
    for (int i = beg; i < end; i++) s += deg[i];
    part[t] = s;
    __syncthreads();
    for (int off = 1; off < 1024; off <<= 1) {
        int v = (t >= off) ? part[t - off] : 0;
        __syncthreads();
        part[t] += v;
        __syncthreads();
    }
    int run = (t == 0) ? 0 : part[t - 1];
    for (int i = beg; i < end; i++) {
        int d = deg[i];
        rowptr[i] = run;
        deg[i] = run;      // cursor for k_fill
        run += d;
    }
    if (t == 1023) rowptr[N_NODES] = run;
}

// fill: eidx (edge id, dst-sorted) and srcs (source node, dst-sorted)
__global__ void k_fill(const int* __restrict__ dst, const int* __restrict__ src,
                       int* __restrict__ cursor,
                       int* __restrict__ eidx, int* __restrict__ srcs) {
    int e = blockIdx.x * 256 + threadIdx.x;
    if (e < M_EDGES) {
        int p = atomicAdd(&cursor[dst[e]], 1);
        eidx[p] = e;
        srcs[p] = src[e];
    }
}

// ---------------------------------------------------------------------------
// esum[i] = sum_{e : dst[e]==i} edge_attr[e]   (depth-invariant, [N,64] f32)
// 16 threads per node, one float4 lane each.
// ---------------------------------------------------------------------------
__global__ __launch_bounds__(256) void k_esum(const float* __restrict__ edge_attr,
                                              const int* __restrict__ rowptr,
                                              const int* __restrict__ eidx,
                                              float* __restrict__ esum) {
    int gid = blockIdx.x * 256 + threadIdx.x;   // over N*16
    int node = gid >> 4, q = gid & 15;
    if (node >= N_NODES) return;
    int beg = rowptr[node], end = rowptr[node + 1];
    float4 acc = make_float4(0.f, 0.f, 0.f, 0.f);
    const float4* E4 = (const float4*)edge_attr;
    for (int i = beg; i < end; i++) {
        int e = eidx[i];
        float4 v = E4[(size_t)e * 16 + q];
        acc.x += v.x; acc.y += v.y; acc.z += v.z; acc.w += v.w;
    }
    ((float4*)esum)[(size_t)node * 16 + q] = acc;
}

// ---------------------------------------------------------------------------
// gather (fused): v[i] = attr[i] + esum_pad[i] + sum_{e : dst[e]==i} attr[srcs]
// one wave (64 lanes x float4) per node; srcs is dst-sorted (sequential).
// Edge loop unrolled x4 -> 4 independent 1KB row loads in flight (was ~1).
// ---------------------------------------------------------------------------
__global__ __launch_bounds__(256) void k_gather(const float* __restrict__ attr,
                                                const int* __restrict__ rowptr,
                                                const int* __restrict__ srcs,
                                                const float* __restrict__ esum,
                                                float* __restrict__ v_out) {
    int gid = blockIdx.x * 256 + threadIdx.x;
    int node = gid >> 6, q = gid & 63;
    if (node >= N_NODES) return;
    int beg = rowptr[node], end = rowptr[node + 1];
    const float4* A4 = (const float4*)attr;
    float4 acc = A4[(size_t)node * 64 + q];          // self term (fused from k_inner)
    if (q >= NODE_F / 4) {
        float4 e = ((const float4*)esum)[(size_t)node * 16 + (q - NODE_F / 4)];
        acc.x += e.x; acc.y += e.y; acc.z += e.z; acc.w += e.w;
    }
    float4 s0 = make_float4(0.f, 0.f, 0.f, 0.f), s1 = s0, s2 = s0, s3 = s0;
    int i = beg;
    for (; i + 4 <= end; i += 4) {
        int n0 = srcs[i], n1 = srcs[i + 1], n2 = srcs[i + 2], n3 = srcs[i + 3];
        float4 v0 = A4[(size_t)n0 * 64 + q];
        float4 v1 = A4[(size_t)n1 * 64 + q];
        float4 v2 = A4[(size_t)n2 * 64 + q];
        float4 v3 = A4[(size_t)n3 * 64 + q];
        s0.x += v0.x; s0.y += v0.y; s0.z += v0.z; s0.w += v0.w;
        s1.x += v1.x; s1.y += v1.y; s1.z += v1.z; s1.w += v1.w;
        s2.x += v2.x; s2.y += v2.y; s2.z += v2.z; s2.w += v2.w;
        s3.x += v3.x; s3.y += v3.y; s3.z += v3.z; s3.w += v3.w;
    }
    for (; i < end; i++) {
        float4 v0 = A4[(size_t)srcs[i] * 64 + q];
        s0.x += v0.x; s0.y += v0.y; s0.z += v0.z; s0.w += v0.w;
    }
    acc.x += s0.x + s1.x + s2.x + s3.x;
    acc.y += s0.y + s1.y + s2.y + s3.y;
    acc.z += s0.z + s1.z + s2.z + s3.z;
    acc.w += s0.w + s1.w + s2.w + s3.w;
    ((float4*)v_out)[(size_t)node * 64 + q] = acc;
}

// ---------------------------------------------------------------------------
// inner GEMM: attr_new = v @ W + b (v precomputed by fused gather).
// 64-row tiles (halves the per-row W_inner stream: 400 -> 200 MB/depth);
// all 4 waves read identical W addresses -> L1-shared.
// ---------------------------------------------------------------------------
__global__ __launch_bounds__(256) void k_inner(const float* __restrict__ v_in,
                                               const float* __restrict__ W,
                                               const float* __restrict__ b,
                                               float* __restrict__ out,
                                               short* __restrict__ out_bf) {
    __shared__ float4 sV[64][64];   // 64 KB
    int tid  = threadIdx.x;
    int row0 = blockIdx.x * 64;

    for (int i = tid; i < 64 * 64; i += 256) {
        int r = i >> 6, q = i & 63;
        int grow = row0 + r;
        float4 v = make_float4(0.f, 0.f, 0.f, 0.f);
        if (grow < N_NODES)
            v = ((const float4*)v_in)[(size_t)grow * 64 + q];
        sV[r][q] = v;
    }
    __syncthreads();

    int cg = tid & 63;
    int rg = tid >> 6;          // 0..3 -> rows rg*16 .. rg*16+15

    float4 acc[16];
#pragma unroll
    for (int r = 0; r < 16; r++) acc[r] = make_float4(0.f, 0.f, 0.f, 0.f);

    const float4* W4 = (const float4*)W;
    for (int k4 = 0; k4 < 64; k4++) {
        float4 w0 = W4[(size_t)(k4 * 4 + 0) * 64 + cg];
        float4 w1 = W4[(size_t)(k4 * 4 + 1) * 64 + cg];
        float4 w2 = W4[(size_t)(k4 * 4 + 2) * 64 + cg];
        float4 w3 = W4[(size_t)(k4 * 4 + 3) * 64 + cg];
#pragma unroll
        for (int r = 0; r < 16; r++) {
            float4 a = sV[rg * 16 + r][k4];
            acc[r].x += a.x * w0.x + a.y * w1.x + a.z * w2.x + a.w * w3.x;
            acc[r].y += a.x * w0.y + a.y * w1.y + a.z * w2.y + a.w * w3.y;
            acc[r].z += a.x * w0.z + a.y * w1.z + a.z * w2.z + a.w * w3.z;
            acc[r].w += a.x * w0.w + a.y * w1.w + a.z * w2.w + a.w * w3.w;
        }
    }

    float4 bb = ((const float4*)b)[cg];
#pragma unroll
    for (int r = 0; r < 16; r++) {
        int grow = row0 + rg * 16 + r;
        if (grow < N_NODES) {
            float4 o = make_float4(acc[r].x + bb.x, acc[r].y + bb.y,
                                   acc[r].z + bb.z, acc[r].w + bb.w);
            ((float4*)out)[(size_t)grow * 64 + cg] = o;
            short4 s; s.x = f2bf(o.x); s.y = f2bf(o.y); s.z = f2bf(o.z); s.w = f2bf(o.w);
            ((short4*)out_bf)[(size_t)grow * 64 + cg] = s;
        }
    }
}

// ---------------------------------------------------------------------------
// W_output swizzle: fp32 [4][256][2048] -> bf16 fragment layout, UNIT-MAJOR:
// unit uu = ks*2 + h is a contiguous 64 KB block of fragments [w][j][lane].
// ---------------------------------------------------------------------------
__global__ void k_wswz(const float* __restrict__ W, short* __restrict__ Wz) {
    int idx = blockIdx.x * 256 + threadIdx.x;    // 2^18 total
    int lane = idx & 63;
    int T    = (idx >> 6) & 127;
    int ks   = (idx >> 13) & 7;
    int d    = idx >> 16;
    int quad = lane >> 4;
    int m    = lane & 15;
    const float* src = W + ((size_t)(d * 256 + ks * 32 + quad * 8)) * 2048 + T * 16 + m;
    int w = T >> 3, h = (T >> 2) & 1, j = T & 3;
    size_t n = ((((size_t)(ks * 2 + h)) * 16 + w) * 4 + j) * 64 + lane;
    short* dstp = Wz + ((size_t)d * 65536 + n) * 8;
#pragma unroll
    for (int jj = 0; jj < 8; jj++) dstp[jj] = f2bf(src[(size_t)jj * 2048]);
}

// ---------------------------------------------------------------------------
// fp contribution via MFMA: fp_part += colsum(softmax(attr @ W + b))
// 32 rows/block, 1024 thr = 16 waves; wave = 32 rows x 128 cols.
// C/D layout: col = lane&15, row = (lane>>4)*4 + reg.
//
// v3: wave-independent register streaming (decisive MSHR-vs-serialization
// experiment). LDS staging for B removed entirely — B fragments are
// lane-exclusive, so each wave streams its own 4 KB/unit straight to VGPRs
// with compiler-counted vmcnt; NO in-loop barriers, no lockstep. A tile
// staged once in LDS (XOR-swizzled source, one barrier). Per-wave staggered
// start spreads aggregate L2 demand. setprio(1) around MFMA (independent-
// wave regime, T5's measured-positive case).
// ---------------------------------------------------------------------------
__global__ __launch_bounds__(1024)
void k_fp_mfma(const short* __restrict__ attr_bf,
               const short* __restrict__ Wz,    // depth offset applied by host
               const float* __restrict__ bias,
               float* __restrict__ fp_part) {
    __shared__ __align__(16) short A_lds[32 * 256];      // 16 KB (swizzled)
    __shared__ float sred[32][17];
    __shared__ float sfinm[32];
    __shared__ float sfinl[32];
    int tid  = threadIdx.x;
    int lane = tid & 63;
    int wave = tid >> 6;          // 0..15
    int quad = lane >> 4;
    int m    = lane & 15;
    int row0 = blockIdx.x * 32;
    int sw   = (m & 7) << 4;      // A-tile XOR swizzle term

    // ---- stage A tile once (swizzled source), single barrier ----
    {
        int r   = tid >> 5;               // row 0..31
        int c16 = tid & 31;               // 16B slot in row
        const char* gsrc = (const char*)attr_bf
            + (size_t)(row0 + r) * 512 + (size_t)((c16 * 16) ^ ((r & 7) << 4));
        GLDS16(gsrc, (char*)A_lds + (size_t)wave * 1024);   // + lane*16 by HW
    }
    asm volatile("s_waitcnt vmcnt(0)" ::: "memory");
    __syncthreads();

    f32x4 acc0[8], acc1[8];
#pragma unroll
    for (int t = 0; t < 8; t++) {
        acc0[t] = (f32x4){0.f, 0.f, 0.f, 0.f};
        acc1[t] = (f32x4){0.f, 0.f, 0.f, 0.f};
    }

    // per-wave B base: fragment f = wave*4 + j of unit u lives at
    // bf16x8 index u*4096 + f*64 + lane  (unit-major Wz layout).
    const bf16x8* Bp = (const bf16x8*)Wz + ((size_t)(wave * 4) * 64 + lane);
    int start = ((blockIdx.x + wave) & 7) << 1;    // even per-wave stagger

    for (int pp = 0; pp < 8; pp++) {
        int u0 = (start + 2 * pp) & 15;            // even; u1 = u0+1
        int ks = u0 >> 1;
        int co = (quad * 16 + ks * 64) ^ sw;
        bf16x8 af0 = *(const bf16x8*)((const char*)A_lds + m * 512 + co);
        bf16x8 af1 = *(const bf16x8*)((const char*)A_lds + (m + 16) * 512 + co);
        const bf16x8* Bu = Bp + (size_t)u0 * 4096;
        bf16x8 b0 = Bu[0], b1 = Bu[64], b2 = Bu[128], b3 = Bu[192];
        const bf16x8* Bv = Bu + 4096;
        bf16x8 c0 = Bv[0], c1 = Bv[64], c2 = Bv[128], c3 = Bv[192];
        __builtin_amdgcn_s_setprio(1);
        acc0[0] = MFMA16(af0, b0, acc0[0]);  acc1[0] = MFMA16(af1, b0, acc1[0]);
        acc0[1] = MFMA16(af0, b1, acc0[1]);  acc1[1] = MFMA16(af1, b1, acc1[1]);
        acc0[2] = MFMA16(af0, b2, acc0[2]);  acc1[2] = MFMA16(af1, b2, acc1[2]);
        acc0[3] = MFMA16(af0, b3, acc0[3]);  acc1[3] = MFMA16(af1, b3, acc1[3]);
        __builtin_amdgcn_s_setprio(0);
        __builtin_amdgcn_s_setprio(1);
        acc0[4] = MFMA16(af0, c0, acc0[4]);  acc1[4] = MFMA16(af1, c0, acc1[4]);
        acc0[5] = MFMA16(af0, c1, acc0[5]);  acc1[5] = MFMA16(af1, c1, acc1[5]);
        acc0[6] = MFMA16(af0, c2, acc0[6]);  acc1[6] = MFMA16(af1, c2, acc1[6]);
        acc0[7] = MFMA16(af0, c3, acc0[7]);  acc1[7] = MFMA16(af1, c3, acc1[7]);
        __builtin_amdgcn_s_setprio(0);
    }

    // bias (col = (wave*8+t)*16 + m)
#pragma unroll
    for (int t = 0; t < 8; t++) {
        float bb = bias[(wave * 8 + t) * 16 + m];
        acc0[t][0] += bb; acc0[t][1] += bb; acc0[t][2] += bb; acc0[t][3] += bb;
        acc1[t][0] += bb; acc1[t][1] += bb; acc1[t][2] += bb; acc1[t][3] += bb;
    }

    // ---- row max ----
    float mx0[4], mx1[4];
#pragma unroll
    for (int r = 0; r < 4; r++) {
        float v0 = acc0[0][r], v1 = acc1[0][r];
#pragma unroll
        for (int t = 1; t < 8; t++) { v0 = fmaxf(v0, acc0[t][r]); v1 = fmaxf(v1, acc1[t][r]); }
        mx0[r] = v0; mx1[r] = v1;
    }
#pragma unroll
    for (int off = 1; off < 16; off <<= 1)
#pragma unroll
        for (int r = 0; r < 4; r++) {
            mx0[r] = fmaxf(mx0[r], __shfl_xor(mx0[r], off));
            mx1[r] = fmaxf(mx1[r], __shfl_xor(mx1[r], off));
        }
    if (m == 0)
#pragma unroll
        for (int r = 0; r < 4; r++) {
            sred[quad * 4 + r][wave]      = mx0[r];
            sred[16 + quad * 4 + r][wave] = mx1[r];
        }
    __syncthreads();
    if (tid < 32) {
        float v = sred[tid][0];
#pragma unroll
        for (int w = 1; w < 16; w++) v = fmaxf(v, sred[tid][w]);
        sfinm[tid] = v;
    }
    __syncthreads();
#pragma unroll
    for (int r = 0; r < 4; r++) { mx0[r] = sfinm[quad * 4 + r]; mx1[r] = sfinm[16 + quad * 4 + r]; }

    // ---- exp + row sum ----
    float ls0[4] = {0.f, 0.f, 0.f, 0.f}, ls1[4] = {0.f, 0.f, 0.f, 0.f};
#pragma unroll
    for (int t = 0; t < 8; t++) {
#pragma unroll
        for (int r = 0; r < 4; r++) {
            float e0 = __expf(acc0[t][r] - mx0[r]);
            float e1 = __expf(acc1[t][r] - mx1[r]);
            acc0[t][r] = e0; acc1[t][r] = e1;
            ls0[r] += e0; ls1[r] += e1;
        }
    }
#pragma unroll
    for (int off = 1; off < 16; off <<= 1)
#pragma unroll
        for (int r = 0; r < 4; r++) {
            ls0[r] += __shfl_xor(ls0[r], off);
            ls1[r] += __shfl_xor(ls1[r], off);
        }
    if (m == 0)
#pragma unroll
        for (int r = 0; r < 4; r++) {
            sred[quad * 4 + r][wave]      = ls0[r];
            sred[16 + quad * 4 + r][wave] = ls1[r];
        }
    __syncthreads();
    if (tid < 32) {
        float v = 0.f;
#pragma unroll
        for (int w = 0; w < 16; w++) v += sred[tid][w];
        sfinl[tid] = v;
    }
    __syncthreads();

    float rinv0[4], rinv1[4];
#pragma unroll
    for (int r = 0; r < 4; r++) {
        int ra = quad * 4 + r, rb = 16 + quad * 4 + r;
        rinv0[r] = (row0 + ra < N_NODES) ? 1.0f / sfinl[ra] : 0.0f;
        rinv1[r] = (row0 + rb < N_NODES) ? 1.0f / sfinl[rb] : 0.0f;
    }

    // ---- column sums over 32 rows -> atomics into replica ----
    float* dst = fp_part + (size_t)(blockIdx.x & 31) * OUT_DIM;
#pragma unroll
    for (int t = 0; t < 8; t++) {
        float cs = acc0[t][0] * rinv0[0] + acc0[t][1] * rinv0[1]
                 + acc0[t][2] * rinv0[2] + acc0[t][3] * rinv0[3]
                 + acc1[t][0] * rinv1[0] + acc1[t][1] * rinv1[1]
                 + acc1[t][2] * rinv1[2] + acc1[t][3] * rinv1[3];
        cs += __shfl_xor(cs, 16);
        cs += __shfl_xor(cs, 32);
        if (quad == 0)
            atomicAdd(&dst[(wave * 8 + t) * 16 + m], cs);
    }
}

// ---------------------------------------------------------------------------
__global__ void k_fp_reduce(const float* __restrict__ part, float* __restrict__ fp) {
    int c = blockIdx.x * 256 + threadIdx.x;   // 2048
    float s = 0.f;
#pragma unroll
    for (int r = 0; r < 32; r++) s += part[(size_t)r * OUT_DIM + c];
    fp[c] = s;
}

// ---------------------------------------------------------------------------
extern "C" void kernel_launch(void* const* d_in, const int* in_sizes, int n_in,
                              void* d_out, int out_size, void* d_ws, size_t ws_size,
                              hipStream_t stream) {
    const float* node_attr = (const float*)d_in[0];
    const float* edge_attr = (const float*)d_in[1];
    const int*   edge_src  = (const int*)d_in[2];
    const int*   edge_dst  = (const int*)d_in[3];
    const float* W_inner   = (const float*)d_in[4];
    const float* b_inner   = (const float*)d_in[5];
    const float* W_output  = (const float*)d_in[6];
    const float* b_output  = (const float*)d_in[7];

    float* fp      = (float*)d_out;
    float* attr    = (float*)d_ws;                        // N*256 f32
    float* agg     = attr + (size_t)N_NODES * DIM;        // N*256 f32 (holds v)
    float* fp_part = agg + (size_t)N_NODES * DIM;         // 32*2048 f32
    short* Wz      = (short*)(fp_part + 32 * OUT_DIM);    // 4*2^16*8 bf16 frags (4 MB)
    int*   deg     = (int*)(Wz + (size_t)4 * 65536 * 8);  // N
    int*   rowptr  = deg + N_NODES;                       // N+1 (+3 pad for alignment)
    int*   eidx    = rowptr + N_NODES + 4;                // M   (pad keeps esum/attr_bf 16B-aligned)
    int*   srcs    = eidx + M_EDGES;                      // M
    float* esum    = (float*)(srcs + M_EDGES);            // N*64 f32 (12.8 MB), 16B-aligned
    short* attr_bf = (short*)(esum + (size_t)N_NODES * EDGE_F); // N_PAD*256 bf16, 16B-aligned

    hipMemsetAsync(fp_part, 0, 32 * OUT_DIM * sizeof(float), stream);
    hipMemsetAsync(deg, 0, N_NODES * sizeof(int), stream);

    k_init_attr<<<(N_PAD * 64 + 255) / 256, 256, 0, stream>>>(node_attr, attr, attr_bf);

    // CSR build (once, reused for all depths)
    k_degree<<<(M_EDGES + 255) / 256, 256, 0, stream>>>(edge_dst, deg);
    k_scan<<<1, 1024, 0, stream>>>(deg, rowptr);
    k_fill<<<(M_EDGES + 255) / 256, 256, 0, stream>>>(edge_dst, edge_src, deg, eidx, srcs);
    k_esum<<<(N_NODES * 16 + 255) / 256, 256, 0, stream>>>(edge_attr, rowptr, eidx, esum);

    // W_output -> bf16 fragment swizzle (all 4 depths, unit-major layout)
    k_wswz<<<1024, 256, 0, stream>>>(W_output, Wz);

    k_fp_mfma<<<N_PAD / 32, 1024, 0, stream>>>(attr_bf, Wz, b_output, fp_part);

    for (int d = 1; d <= DEPTH; d++) {
        k_gather<<<(N_NODES * 64 + 255) / 256, 256, 0, stream>>>(
            attr, rowptr, srcs, esum, agg);                 // agg <- v (fused add)
        k_inner<<<(N_NODES + 63) / 64, 256, 0, stream>>>(
            agg, W_inner + (size_t)(d - 1) * DIM * DIM,
            b_inner + (size_t)(d - 1) * DIM, attr, attr_bf);
        k_fp_mfma<<<N_PAD / 32, 1024, 0, stream>>>(
            attr_bf, Wz + (size_t)d * 65536 * 8,
            b_output + (size_t)d * OUT_DIM, fp_part);
    }
    k_fp_reduce<<<OUT_DIM / 256, 256, 0, stream>>>(fp_part, fp);
}